// Round 9
// baseline (489.667 us; speedup 1.0000x reference)
//
#include <hip/hip_runtime.h>
#include <stdint.h>

#define B_ 2
#define T_ 2048
#define P_ 1024
#define H_ 16
#define D_ 128
#define C_ 2048
#define S_ 3072   // P_ + T_
#define M_ 4096   // B_*T_
#define N3_ 6144  // 3*C_

typedef unsigned short u16;
typedef unsigned int uint32;
typedef __attribute__((ext_vector_type(8))) short short8;
typedef __attribute__((ext_vector_type(8))) __bf16 bf16x8;
typedef __attribute__((ext_vector_type(4))) float f32x4;
typedef __attribute__((ext_vector_type(16))) float f32x16;
typedef __attribute__((ext_vector_type(4))) unsigned short u16x4;
typedef __attribute__((ext_vector_type(4))) unsigned int uint4v;

static __device__ __forceinline__ float bf2f(u16 h) {
    union { unsigned int u; float f; } x; x.u = ((unsigned int)h) << 16; return x.f;
}
static __device__ __forceinline__ u16 f2bf(float f) {
    return __builtin_bit_cast(u16, (__bf16)f);   // v_cvt: RNE, 1 op
}
static __device__ __forceinline__ uint32 cvtpk(float lo, float hi) {
    uint32 r;                                    // D[15:0]=bf16(S0), D[31:16]=bf16(S1)
    asm("v_cvt_pk_bf16_f32 %0, %1, %2" : "=v"(r) : "v"(lo), "v"(hi));
    return r;
}
#define MAX3(a, b, c) fmaxf(fmaxf((a), (b)), (c))   // fuses to v_max3_f32

static __device__ __forceinline__ f32x16 mfma32(short8 a, short8 b, f32x16 c) {
    return __builtin_amdgcn_mfma_f32_32x32x16_bf16(
        __builtin_bit_cast(bf16x8, a), __builtin_bit_cast(bf16x8, b), c, 0, 0, 0);
}

typedef __attribute__((address_space(3))) unsigned int lds_u32;
typedef const __attribute__((address_space(1))) unsigned int glb_u32;
static __device__ __forceinline__ void gload_lds16(const void* g, void* l) {
    __builtin_amdgcn_global_load_lds((glb_u32*)g, (lds_u32*)l, 16, 0, 0);
}

static __device__ __forceinline__ void storeC(float* p, float v) { *p = v; }
static __device__ __forceinline__ void storeC(u16* p, float v) { *p = f2bf(v); }

// ---------------------------------------------------------------- prep kernels

__global__ void castx_kernel(const float* __restrict__ x, u16* __restrict__ Xb) {
    int idx = blockIdx.x * 256 + threadIdx.x;          // over (M_*C_)/4
    const float4 v = ((const float4*)x)[idx];
    u16x4 o;
    o.x = f2bf(v.x); o.y = f2bf(v.y); o.z = f2bf(v.z); o.w = f2bf(v.w);
    ((u16x4*)Xb)[idx] = o;
}

// W[K,N] f32 -> Wt[N,K] bf16, 64x64 LDS tiles
__global__ void wT_kernel(const float* __restrict__ W, u16* __restrict__ Wt,
                          int Ndim, int Kdim) {
    __shared__ float tile[64][65];
    const int n0 = blockIdx.x * 64, k0 = blockIdx.y * 64;
    const int tid = threadIdx.x;
#pragma unroll
    for (int i = 0; i < 16; i++) {
        int idx = tid + i * 256;
        int r = idx >> 6, c = idx & 63;                // r: k, c: n
        tile[r][c] = W[(size_t)(k0 + r) * Ndim + n0 + c];
    }
    __syncthreads();
#pragma unroll
    for (int i = 0; i < 16; i++) {
        int idx = tid + i * 256;
        int r = idx >> 6, c = idx & 63;                // r: n, c: k
        Wt[(size_t)(n0 + r) * Kdim + k0 + c] = f2bf(tile[c][r]);
    }
}

__global__ void rope_table_kernel(float* __restrict__ cosT, float* __restrict__ sinT) {
    int idx = blockIdx.x * 256 + threadIdx.x;          // T_*64
    int t = idx >> 6, d = idx & 63;
    float inv = powf(10000.0f, -(float)d * (1.0f / 64.0f));
    float ang = (float)(P_ + t) * inv;
    cosT[idx] = cosf(ang);
    sinT[idx] = sinf(ang);
}

// RoPE Q in place; RoPE K and scatter into Kc[b,h,P_+t,d]
__global__ void rope_qk_kernel(u16* __restrict__ QKVb, u16* __restrict__ Kc,
                               const float* __restrict__ cosT,
                               const float* __restrict__ sinT) {
    int idx = blockIdx.x * 256 + threadIdx.x;          // B_*T_*H_*64
    int d = idx & 63;
    int h = (idx >> 6) & 15;
    int t = (idx >> 10) & 2047;
    int b = idx >> 21;
    size_t rowoff = (size_t)(b * T_ + t) * N3_;
    float c = cosT[(t << 6) + d], s = sinT[(t << 6) + d];
    {   // Q
        u16* p1 = QKVb + rowoff + h * 128 + d;
        float x1 = bf2f(p1[0]), x2 = bf2f(p1[64]);
        p1[0]  = f2bf(x1 * c - x2 * s);
        p1[64] = f2bf(x2 * c + x1 * s);
    }
    {   // K -> cache
        const u16* p1 = QKVb + rowoff + C_ + h * 128 + d;
        float x1 = bf2f(p1[0]), x2 = bf2f(p1[64]);
        u16* o = Kc + ((size_t)(b * H_ + h) * S_ + P_ + t) * 128 + d;
        o[0]  = f2bf(x1 * c - x2 * s);
        o[64] = f2bf(x2 * c + x1 * s);
    }
}

__global__ void pastk_kernel(const float* __restrict__ past_k, u16* __restrict__ Kc) {
    int idx = blockIdx.x * 256 + threadIdx.x;          // B_*H_*P_*D_
    int d = idx & 127;
    int p = (idx >> 7) & 1023;
    int bh = idx >> 17;
    Kc[((size_t)bh * S_ + p) * 128 + d] = f2bf(past_k[idx]);
}

// new V (bf16 in QKVb) -> Vt[b,h,d,P_+t]
__global__ void vnewT_kernel(const u16* __restrict__ QKVb, u16* __restrict__ Vt) {
    __shared__ u16 tile[64][65];
    const int t0 = blockIdx.x * 64, d0 = blockIdx.y * 64, bh = blockIdx.z;
    const int b = bh >> 4, h = bh & 15;
    const int tid = threadIdx.x;
#pragma unroll
    for (int i = 0; i < 16; i++) {
        int idx = tid + i * 256;
        int r = idx >> 6, c = idx & 63;                // r: t, c: d
        tile[r][c] = QKVb[(size_t)(b * T_ + t0 + r) * N3_ + 2 * C_ + h * 128 + d0 + c];
    }
    __syncthreads();
#pragma unroll
    for (int i = 0; i < 16; i++) {
        int idx = tid + i * 256;
        int r = idx >> 6, c = idx & 63;                // r: d, c: t
        Vt[((size_t)bh * 128 + d0 + r) * S_ + P_ + t0 + c] = tile[c][r];
    }
}

// past V f32 -> Vt[b,h,d,p]
__global__ void vpastT_kernel(const float* __restrict__ past_v, u16* __restrict__ Vt) {
    __shared__ float tile[64][65];
    const int p0 = blockIdx.x * 64, d0 = blockIdx.y * 64, bh = blockIdx.z;
    const int tid = threadIdx.x;
#pragma unroll
    for (int i = 0; i < 16; i++) {
        int idx = tid + i * 256;
        int r = idx >> 6, c = idx & 63;                // r: p, c: d
        tile[r][c] = past_v[((size_t)bh * P_ + p0 + r) * 128 + d0 + c];
    }
    __syncthreads();
#pragma unroll
    for (int i = 0; i < 16; i++) {
        int idx = tid + i * 256;
        int r = idx >> 6, c = idx & 63;                // r: d, c: p
        Vt[((size_t)bh * 128 + d0 + r) * S_ + p0 + c] = f2bf(tile[c][r]);
    }
}

// ---------------------------------------------------------------- GEMM (3-buf)
// C[M,N] = A[M,K] * Bt[N,K]^T ; bf16 in, OutT out.
// BM=256, BN=128, BK=64, NBUF=3 (LDS 144 KiB). 8 waves (4m x 2n), per-wave
// 64x64 C via 2x2 mfma_32x32x16 frags. Counted-vmcnt pipeline (T4):
// iteration t waits vmcnt(6) -- tile t+1's 6 loads STAY in flight across the
// barrier -- then issues tile t+2 into buf[(t+2)%3]. One barrier per K-step,
// no mid-loop drain. LDS rows 128 B, XOR-swizzle ((row&7)<<4) via
// pre-swizzled global source (rule #21).
template <typename OutT>
__global__ void __launch_bounds__(512, 1)
gemm3(const u16* __restrict__ A, const u16* __restrict__ Bt,
      OutT* __restrict__ Co, int Mdim, int Ndim, int Kdim) {
    __shared__ u16 lA[3 * 256 * 64];   // 96 KiB
    __shared__ u16 lB[3 * 128 * 64];   // 48 KiB
    const int nbx = Ndim >> 7;
    const int nwg = (Mdim >> 8) * nbx;
    int bid = blockIdx.x;
    int wg = (bid & 7) * (nwg >> 3) + (bid >> 3);      // XCD swizzle (nwg%8==0)
    const int bm = wg / nbx, bn = wg % nbx;
    const int m0 = bm << 8, n0 = bn << 7;
    const int tid = threadIdx.x;
    const int wave = tid >> 6, lane = tid & 63;
    const int mw = wave >> 1, nw = wave & 1;
    const int l31 = lane & 31, hi = lane >> 5;

    f32x16 acc[2][2];
#pragma unroll
    for (int i = 0; i < 2; i++)
#pragma unroll
        for (int j = 0; j < 2; j++) acc[i][j] = (f32x16)(0.0f);

    // staging sources: chunk cid = i*512 + tid; row = cid>>3, physical chunk
    // pc = cid&7 holds logical chunk pc^(row&7) (inverse-swizzled source).
    const u16* aSrc[4];
    const u16* bSrc[2];
#pragma unroll
    for (int i = 0; i < 4; i++) {
        int cid = i * 512 + tid;
        int r = cid >> 3, pc = cid & 7;
        aSrc[i] = A + (size_t)(m0 + r) * Kdim + ((pc ^ (r & 7)) << 3);
    }
#pragma unroll
    for (int i = 0; i < 2; i++) {
        int cid = i * 512 + tid;
        int r = cid >> 3, pc = cid & 7;
        bSrc[i] = Bt + (size_t)(n0 + r) * Kdim + ((pc ^ (r & 7)) << 3);
    }

#define STAGE3(bi, kt) do {                                                     \
    u16* _pa = lA + (bi) * 16384 + wave * 512;                                  \
    u16* _pb = lB + (bi) * 8192 + wave * 512;                                   \
    _Pragma("unroll")                                                           \
    for (int i = 0; i < 4; i++)                                                 \
        gload_lds16(aSrc[i] + (size_t)(kt) * 64, _pa + i * 4096);               \
    _Pragma("unroll")                                                           \
    for (int i = 0; i < 2; i++)                                                 \
        gload_lds16(bSrc[i] + (size_t)(kt) * 64, _pb + i * 4096);               \
} while (0)

    STAGE3(0, 0);
    STAGE3(1, 1);

    const int NT = Kdim >> 6;
    int bc = 0;
    for (int t = 0; t < NT; ++t) {
        if (t + 1 < NT) asm volatile("s_waitcnt vmcnt(6)" ::: "memory");
        else            asm volatile("s_waitcnt vmcnt(0)" ::: "memory");
        __builtin_amdgcn_s_barrier();
        asm volatile("" ::: "memory");
        if (t + 2 < NT) {
            int b2 = bc + 2; if (b2 >= 3) b2 -= 3;
            STAGE3(b2, t + 2);
        }
        const u16* la = lA + bc * 16384;
        const u16* lb = lB + bc * 8192;
        // A frag: row = mw*64 + mi*32 + l31, k-slice ks: bytes ks*32 + hi*16
        short8 af[2][4], bf[2][4];
#pragma unroll
        for (int mi = 0; mi < 2; mi++)
#pragma unroll
            for (int ks = 0; ks < 4; ks++) {
                int r = mw * 64 + mi * 32 + l31;
                int cb = ((ks << 5) + (hi << 4)) ^ ((r & 7) << 4);
                af[mi][ks] = *(const short8*)&la[r * 64 + (cb >> 1)];
            }
#pragma unroll
        for (int nj = 0; nj < 2; nj++)
#pragma unroll
            for (int ks = 0; ks < 4; ks++) {
                int r = nw * 64 + nj * 32 + l31;
                int cb = ((ks << 5) + (hi << 4)) ^ ((r & 7) << 4);
                bf[nj][ks] = *(const short8*)&lb[r * 64 + (cb >> 1)];
            }
        __builtin_amdgcn_s_setprio(1);
#pragma unroll
        for (int ks = 0; ks < 4; ks++)
#pragma unroll
            for (int mi = 0; mi < 2; mi++)
#pragma unroll
                for (int nj = 0; nj < 2; nj++)
                    acc[mi][nj] = mfma32(af[mi][ks], bf[nj][ks], acc[mi][nj]);
        __builtin_amdgcn_s_setprio(0);
        __builtin_amdgcn_sched_barrier(0);   // rule #18: pin MFMA/lgkm here
        bc = bc + 1; if (bc >= 3) bc = 0;
    }
#undef STAGE3

    // epilogue: D row = (reg&3) + 8*(reg>>2) + 4*hi, col = l31 (m74/m101)
#pragma unroll
    for (int mi = 0; mi < 2; mi++)
#pragma unroll
        for (int nj = 0; nj < 2; nj++) {
            int col = n0 + nw * 64 + nj * 32 + l31;
#pragma unroll
            for (int g = 0; g < 4; g++) {
                int row = m0 + mw * 64 + mi * 32 + g * 8 + hi * 4;
#pragma unroll
                for (int q = 0; q < 4; q++)
                    storeC(&Co[(size_t)(row + q) * Ndim + col],
                           acc[mi][nj][g * 4 + q]);
            }
        }
}

// ---------------------------------------------------------------- attention
// 4 waves x 32 q-rows = 128 q/block; 512 blocks. Swapped QK^T / swapped PV,
// in-register softmax (max3-tree, 4-way partial sums, cvt_pk packing), T13
// defer-max. R8: V is NOT LDS-staged (catalog #7: tile is L1/L2-resident and
// LDS pipe was the bottleneck) -- V^T frags load global->reg at tile top,
// latency hidden under QK^T+softmax; K stays LDS dbuf + XOR-swizzle.
__global__ void __launch_bounds__(256, 2)
attn_kernel(const u16* __restrict__ QKVb, const u16* __restrict__ Kc,
            const u16* __restrict__ Vt, u16* __restrict__ O) {
    __shared__ u16 ldsK[2][64 * 128];   // [buf][64 k][128 d], rows 256B

    int bid = blockIdx.x;                              // 512 blocks
    int wg = (bid & 7) * 64 + (bid >> 3);              // XCD swizzle (bijective)
    const int qc = wg & 15;                            // q-chunk (16 x 128 rows)
    const int bh = wg >> 4;
    const int b = bh >> 4, h = bh & 15;
    const int tid = threadIdx.x, wave = tid >> 6, lane = tid & 63;
    const int l31 = lane & 31, hi = lane >> 5;

    // K staging constants (256 thr): source pre-swizzled; LDS dest linear.
    const int krow = tid >> 4;                                         // 0..15
    const int kcol = (((tid & 15) << 4) ^ ((krow & 7) << 4)) >> 1;

    const u16* Kbh = Kc + (size_t)bh * S_ * 128;
    const u16* Vbh = Vt + (size_t)bh * 128 * S_;
    // V^T frag base: row = dblk*32 + l31, col = ks*16 + hi*8 (+ s0 per tile)
    const u16* Vln = Vbh + (size_t)l31 * S_ + hi * 8;

    const int tq = qc * 128 + wave * 32 + l31;         // this lane's q row
    // Q fragments: Q[q=l31][d = ks*16 + hi*8 + e], 8 x bf16x8
    short8 qf[8];
    {
        const u16* qp = QKVb + (size_t)(b * T_ + tq) * N3_ + h * 128 + hi * 8;
#pragma unroll
        for (int ks = 0; ks < 8; ks++) qf[ks] = *(const short8*)(qp + ks * 16);
    }

    f32x16 acco[4];                                    // O^T: col q=l31, row d
#pragma unroll
    for (int d = 0; d < 4; d++) acco[d] = (f32x16)(0.0f);
    float mrow = -1e30f, lrow = 0.f;                   // per-lane (q = l31)
    const float sl2 = 0.08838834764831845f * 1.4426950408889634f;

#define STAGEK(bufi, tt) do {                                                   \
    const int _s0 = (tt) * 64;                                                  \
    _Pragma("unroll")                                                           \
    for (int i = 0; i < 4; i++)                                                 \
        gload_lds16(Kbh + (size_t)(_s0 + krow + i * 16) * 128 + kcol,           \
                    (char*)&ldsK[bufi][0] + i * 4096 + wave * 1024);            \
} while (0)

    STAGEK(0, 0);
    __syncthreads();

    const int swz = (l31 & 7) << 4;                    // read-side swizzle

    for (int t = 0; t < S_ / 64; ++t) {
        const int cur = t & 1;
        const int s0 = t * 64;

        // ---- issue V^T reg loads for THIS tile (L1/L2; retire before PV) ----
        short8 vf[4][4];                               // [ks][dblk]
#pragma unroll
        for (int ks = 0; ks < 4; ks++)
#pragma unroll
            for (int dblk = 0; dblk < 4; dblk++)
                vf[ks][dblk] = *(const short8*)(Vln + (size_t)(dblk * 32) * S_
                                                + s0 + ks * 16);
        __builtin_amdgcn_sched_barrier(0);             // pin V loads early

        // ---- issue K staging for NEXT tile (drained at tile-end barrier) ----
        if (t < S_ / 64 - 1) STAGEK(cur ^ 1, t + 1);

        const u16* Kl = ldsK[cur];

        // ---- QK^T: p0 (k 0..31), p1 (k 32..63); contraction d ----
        f32x16 p0 = (f32x16)(0.0f), p1 = (f32x16)(0.0f);
        __builtin_amdgcn_s_setprio(1);
#pragma unroll
        for (int ks = 0; ks < 8; ks++) {
            const int cidx = (((ks * 32 + hi * 16) ^ swz) >> 1);
            short8 k0 = *(const short8*)&Kl[(l31 << 7) + cidx];
            short8 k1 = *(const short8*)&Kl[((32 + l31) << 7) + cidx];
            p0 = mfma32(k0, qf[ks], p0);
            p1 = mfma32(k1, qf[ks], p1);
        }
        __builtin_amdgcn_s_setprio(0);

        // ---- online softmax, in-register (q = l31) ----
        float t0 = MAX3(p0[0], p0[1], p0[2]);
        float t1 = MAX3(p0[3], p0[4], p0[5]);
        float t2 = MAX3(p0[6], p0[7], p0[8]);
        float t3 = MAX3(p0[9], p0[10], p0[11]);
        float t4 = MAX3(p0[12], p0[13], p0[14]);
        float t5 = MAX3(p0[15], p1[0], p1[1]);
        float t6 = MAX3(p1[2], p1[3], p1[4]);
        float t7 = MAX3(p1[5], p1[6], p1[7]);
        float t8 = MAX3(p1[8], p1[9], p1[10]);
        float t9 = MAX3(p1[11], p1[12], p1[13]);
        float u0 = MAX3(t0, t1, t2);
        float u1 = MAX3(t3, t4, t5);
        float u2 = MAX3(t6, t7, t8);
        float u3 = MAX3(t9, p1[14], p1[15]);
        float pm = fmaxf(MAX3(u0, u1, u2), u3);
        pm = fmaxf(pm, __shfl_xor(pm, 32));
        float pmS = pm * sl2;
        if (!__all(pmS <= mrow + 8.0f)) {              // T13 defer-max
            float mn = fmaxf(mrow, pmS);
            float fac = exp2f(mrow - mn);
            mrow = mn;
            lrow *= fac;
#pragma unroll
            for (int d = 0; d < 4; d++)
#pragma unroll
                for (int r = 0; r < 16; r++) acco[d][r] *= fac;
        }
        float s0a = 0.f, s1a = 0.f, s2a = 0.f, s3a = 0.f;
#pragma unroll
        for (int r = 0; r < 16; r += 4) {
            p0[r + 0] = exp2f(fmaf(p0[r + 0], sl2, -mrow)); s0a += p0[r + 0];
            p0[r + 1] = exp2f(fmaf(p0[r + 1], sl2, -mrow)); s1a += p0[r + 1];
            p0[r + 2] = exp2f(fmaf(p0[r + 2], sl2, -mrow)); s2a += p0[r + 2];
            p0[r + 3] = exp2f(fmaf(p0[r + 3], sl2, -mrow)); s3a += p0[r + 3];
        }
#pragma unroll
        for (int r = 0; r < 16; r += 4) {
            p1[r + 0] = exp2f(fmaf(p1[r + 0], sl2, -mrow)); s0a += p1[r + 0];
            p1[r + 1] = exp2f(fmaf(p1[r + 1], sl2, -mrow)); s1a += p1[r + 1];
            p1[r + 2] = exp2f(fmaf(p1[r + 2], sl2, -mrow)); s2a += p1[r + 2];
            p1[r + 3] = exp2f(fmaf(p1[r + 3], sl2, -mrow)); s3a += p1[r + 3];
        }
        float sum = (s0a + s1a) + (s2a + s3a);
        sum += __shfl_xor(sum, 32);
        lrow += sum;

        // ---- P (C-layout) -> PV B-frags, in-register (T12: cvt_pk + shfl) ----
        uint32 w[4][4];
#define PACK_HALF(pp, kh, ksout) do {                                           \
    uint32 A0 = cvtpk(pp[(kh)*8 + 0], pp[(kh)*8 + 1]);                          \
    uint32 A1 = cvtpk(pp[(kh)*8 + 2], pp[(kh)*8 + 3]);                          \
    uint32 B0 = cvtpk(pp[(kh)*8 + 4], pp[(kh)*8 + 5]);                          \
    uint32 B1 = cvtpk(pp[(kh)*8 + 6], pp[(kh)*8 + 7]);                          \
    uint32 sA0 = __shfl_xor(A0, 32), sA1 = __shfl_xor(A1, 32);                  \
    uint32 sB0 = __shfl_xor(B0, 32), sB1 = __shfl_xor(B1, 32);                  \
    w[ksout][0] = hi ? sB0 : A0;                                                \
    w[ksout][1] = hi ? sB1 : A1;                                                \
    w[ksout][2] = hi ? B0 : sA0;                                                \
    w[ksout][3] = hi ? B1 : sA1;                                                \
} while (0)
        PACK_HALF(p0, 0, 0);
        PACK_HALF(p0, 1, 1);
        PACK_HALF(p1, 0, 2);
        PACK_HALF(p1, 1, 3);
#undef PACK_HALF

        // ---- PV: O^T[d][q] += V^T[d][k] * P^T[k][q] (V from registers) ----
        __builtin_amdgcn_s_setprio(1);
#pragma unroll
        for (int ks = 0; ks < 4; ks++) {
            uint4v pw = {w[ks][0], w[ks][1], w[ks][2], w[ks][3]};
            short8 pf = __builtin_bit_cast(short8, pw);
#pragma unroll
            for (int dblk = 0; dblk < 4; dblk++)
                acco[dblk] = mfma32(vf[ks][dblk], pf, acco[dblk]);
        }
        __builtin_amdgcn_s_setprio(0);

        __syncthreads();   // readers done with cur; K stage(cur^1) drained
    }
#undef STAGEK

    // ---- epilogue: O[b*T+tq][h*128+d], d = dblk*32 + 8*j + 4*hi + {0..3} ----
    float rl = 1.0f / lrow;
    u16* Op = O + (size_t)(b * T_ + tq) * C_ + h * 128;
#pragma unroll
    for (int dblk = 0; dblk < 4; dblk++)
#pragma unroll
        for (int j = 0; j < 4; j++) {
            u16x4 o;
            o.x = f2bf(acco[dblk][4 * j + 0] * rl);
            o.y = f2bf(acco[dblk][4 * j + 1] * rl);
            o.z = f2bf(acco[dblk][4 * j + 2] * rl);
            o.w = f2bf(acco[dblk][4 * j + 3] * rl);
            *(u16x4*)(Op + dblk * 32 + j * 8 + hi * 4) = o;
        }
}

// ---------------------------------------------------------------- launch

extern "C" void kernel_launch(void* const* d_in, const int* in_sizes, int n_in,
                              void* d_out, int out_size, void* d_ws, size_t ws_size,
                              hipStream_t stream) {
    const float* x      = (const float*)d_in[0];
    const float* w_qkv  = (const float*)d_in[1];
    const float* w_out  = (const float*)d_in[2];
    const float* past_k = (const float*)d_in[3];
    const float* past_v = (const float*)d_in[4];
    float* out = (float*)d_out;

    char* ws = (char*)d_ws;
    u16* Xb    = (u16*)(ws);                            // 16 MB
    u16* Wqkvt = (u16*)(ws + 16777216);                 // 24 MB
    u16* Woutt = (u16*)(ws + 41943040);                 //  8 MB
    u16* QKVb  = (u16*)(ws + 50331648);                 // 48 MB
    u16* Kc    = (u16*)(ws + 100663296);                // 24 MB
    u16* Vt    = (u16*)(ws + 125829120);                // 24 MB
    u16* O     = (u16*)(ws + 150994944);                // 16 MB
    float* cosT = (float*)(ws + 167772160);             // 0.5 MB
    float* sinT = (float*)(ws + 168296448);             // 0.5 MB

    castx_kernel<<<(M_ * C_ / 4) / 256, 256, 0, stream>>>(x, Xb);
    wT_kernel<<<dim3(N3_ / 64, C_ / 64), 256, 0, stream>>>(w_qkv, Wqkvt, N3_, C_);
    wT_kernel<<<dim3(C_ / 64, C_ / 64), 256, 0, stream>>>(w_out, Woutt, C_, C_);
    rope_table_kernel<<<(T_ * 64) / 256, 256, 0, stream>>>(cosT, sinT);

    gemm3<u16><<<(M_ / 256) * (N3_ / 128), 512, 0, stream>>>(Xb, Wqkvt, QKVb, M_, N3_, C_);

    rope_qk_kernel<<<(B_ * T_ * H_ * 64) / 256, 256, 0, stream>>>(QKVb, Kc, cosT, sinT);
    pastk_kernel<<<(B_ * H_ * P_ * D_) / 256, 256, 0, stream>>>(past_k, Kc);
    vnewT_kernel<<<dim3(T_ / 64, 2, B_ * H_), 256, 0, stream>>>(QKVb, Vt);
    vpastT_kernel<<<dim3(P_ / 64, 2, B_ * H_), 256, 0, stream>>>(past_v, Vt);

    attn_kernel<<<512, 256, 0, stream>>>(QKVb, Kc, Vt, O);

    gemm3<float><<<(M_ / 256) * (C_ / 128), 512, 0, stream>>>(O, Woutt, out, M_, C_, C_);
}

// Round 10
// 383.236 us; speedup vs baseline: 1.2777x; 1.2777x over previous
//
#include <hip/hip_runtime.h>
#include <stdint.h>

#define B_ 2
#define T_ 2048
#define P_ 1024
#define H_ 16
#define D_ 128
#define C_ 2048
#define S_ 3072   // P_ + T_
#define M_ 4096   // B_*T_
#define N3_ 6144  // 3*C_

typedef unsigned short u16;
typedef unsigned int uint32;
typedef __attribute__((ext_vector_type(8))) short short8;
typedef __attribute__((ext_vector_type(8))) __bf16 bf16x8;
typedef __attribute__((ext_vector_type(4))) float f32x4;
typedef __attribute__((ext_vector_type(16))) float f32x16;
typedef __attribute__((ext_vector_type(4))) unsigned short u16x4;
typedef __attribute__((ext_vector_type(4))) unsigned int uint4v;

static __device__ __forceinline__ float bf2f(u16 h) {
    union { unsigned int u; float f; } x; x.u = ((unsigned int)h) << 16; return x.f;
}
static __device__ __forceinline__ u16 f2bf(float f) {
    return __builtin_bit_cast(u16, (__bf16)f);   // v_cvt: RNE, 1 op
}
static __device__ __forceinline__ uint32 cvtpk(float lo, float hi) {
    uint32 r;                                    // D[15:0]=bf16(S0), D[31:16]=bf16(S1)
    asm("v_cvt_pk_bf16_f32 %0, %1, %2" : "=v"(r) : "v"(lo), "v"(hi));
    return r;
}
#define MAX3(a, b, c) fmaxf(fmaxf((a), (b)), (c))   // fuses to v_max3_f32

static __device__ __forceinline__ f32x4 mfma_bf16(short8 a, short8 b, f32x4 c) {
    return __builtin_amdgcn_mfma_f32_16x16x32_bf16(
        __builtin_bit_cast(bf16x8, a), __builtin_bit_cast(bf16x8, b), c, 0, 0, 0);
}
static __device__ __forceinline__ f32x16 mfma32(short8 a, short8 b, f32x16 c) {
    return __builtin_amdgcn_mfma_f32_32x32x16_bf16(
        __builtin_bit_cast(bf16x8, a), __builtin_bit_cast(bf16x8, b), c, 0, 0, 0);
}

typedef __attribute__((address_space(3))) unsigned int lds_u32;
typedef const __attribute__((address_space(1))) unsigned int glb_u32;
static __device__ __forceinline__ void gload_lds16(const void* g, void* l) {
    __builtin_amdgcn_global_load_lds((glb_u32*)g, (lds_u32*)l, 16, 0, 0);
}

static __device__ __forceinline__ void storeC(float* p, float v) { *p = v; }
static __device__ __forceinline__ void storeC(u16* p, float v) { *p = f2bf(v); }

// ---------------------------------------------------------------- prep kernels

__global__ void castx_kernel(const float* __restrict__ x, u16* __restrict__ Xb) {
    int idx = blockIdx.x * 256 + threadIdx.x;          // over (M_*C_)/4
    const float4 v = ((const float4*)x)[idx];
    u16x4 o;
    o.x = f2bf(v.x); o.y = f2bf(v.y); o.z = f2bf(v.z); o.w = f2bf(v.w);
    ((u16x4*)Xb)[idx] = o;
}

// W[K,N] f32 -> Wt[N,K] bf16, 64x64 LDS tiles
__global__ void wT_kernel(const float* __restrict__ W, u16* __restrict__ Wt,
                          int Ndim, int Kdim) {
    __shared__ float tile[64][65];
    const int n0 = blockIdx.x * 64, k0 = blockIdx.y * 64;
    const int tid = threadIdx.x;
#pragma unroll
    for (int i = 0; i < 16; i++) {
        int idx = tid + i * 256;
        int r = idx >> 6, c = idx & 63;                // r: k, c: n
        tile[r][c] = W[(size_t)(k0 + r) * Ndim + n0 + c];
    }
    __syncthreads();
#pragma unroll
    for (int i = 0; i < 16; i++) {
        int idx = tid + i * 256;
        int r = idx >> 6, c = idx & 63;                // r: n, c: k
        Wt[(size_t)(n0 + r) * Kdim + k0 + c] = f2bf(tile[c][r]);
    }
}

__global__ void rope_table_kernel(float* __restrict__ cosT, float* __restrict__ sinT) {
    int idx = blockIdx.x * 256 + threadIdx.x;          // T_*64
    int t = idx >> 6, d = idx & 63;
    float inv = powf(10000.0f, -(float)d * (1.0f / 64.0f));
    float ang = (float)(P_ + t) * inv;
    cosT[idx] = cosf(ang);
    sinT[idx] = sinf(ang);
}

// RoPE Q in place; RoPE K and scatter into Kc[b,h,P_+t,d]
__global__ void rope_qk_kernel(u16* __restrict__ QKVb, u16* __restrict__ Kc,
                               const float* __restrict__ cosT,
                               const float* __restrict__ sinT) {
    int idx = blockIdx.x * 256 + threadIdx.x;          // B_*T_*H_*64
    int d = idx & 63;
    int h = (idx >> 6) & 15;
    int t = (idx >> 10) & 2047;
    int b = idx >> 21;
    size_t rowoff = (size_t)(b * T_ + t) * N3_;
    float c = cosT[(t << 6) + d], s = sinT[(t << 6) + d];
    {   // Q
        u16* p1 = QKVb + rowoff + h * 128 + d;
        float x1 = bf2f(p1[0]), x2 = bf2f(p1[64]);
        p1[0]  = f2bf(x1 * c - x2 * s);
        p1[64] = f2bf(x2 * c + x1 * s);
    }
    {   // K -> cache
        const u16* p1 = QKVb + rowoff + C_ + h * 128 + d;
        float x1 = bf2f(p1[0]), x2 = bf2f(p1[64]);
        u16* o = Kc + ((size_t)(b * H_ + h) * S_ + P_ + t) * 128 + d;
        o[0]  = f2bf(x1 * c - x2 * s);
        o[64] = f2bf(x2 * c + x1 * s);
    }
}

__global__ void pastk_kernel(const float* __restrict__ past_k, u16* __restrict__ Kc) {
    int idx = blockIdx.x * 256 + threadIdx.x;          // B_*H_*P_*D_
    int d = idx & 127;
    int p = (idx >> 7) & 1023;
    int bh = idx >> 17;
    Kc[((size_t)bh * S_ + p) * 128 + d] = f2bf(past_k[idx]);
}

// new V (bf16 in QKVb) -> Vt[b,h,d,P_+t]
__global__ void vnewT_kernel(const u16* __restrict__ QKVb, u16* __restrict__ Vt) {
    __shared__ u16 tile[64][65];
    const int t0 = blockIdx.x * 64, d0 = blockIdx.y * 64, bh = blockIdx.z;
    const int b = bh >> 4, h = bh & 15;
    const int tid = threadIdx.x;
#pragma unroll
    for (int i = 0; i < 16; i++) {
        int idx = tid + i * 256;
        int r = idx >> 6, c = idx & 63;                // r: t, c: d
        tile[r][c] = QKVb[(size_t)(b * T_ + t0 + r) * N3_ + 2 * C_ + h * 128 + d0 + c];
    }
    __syncthreads();
#pragma unroll
    for (int i = 0; i < 16; i++) {
        int idx = tid + i * 256;
        int r = idx >> 6, c = idx & 63;                // r: d, c: t
        Vt[((size_t)bh * 128 + d0 + r) * S_ + P_ + t0 + c] = tile[c][r];
    }
}

// past V f32 -> Vt[b,h,d,p]
__global__ void vpastT_kernel(const float* __restrict__ past_v, u16* __restrict__ Vt) {
    __shared__ float tile[64][65];
    const int p0 = blockIdx.x * 64, d0 = blockIdx.y * 64, bh = blockIdx.z;
    const int tid = threadIdx.x;
#pragma unroll
    for (int i = 0; i < 16; i++) {
        int idx = tid + i * 256;
        int r = idx >> 6, c = idx & 63;                // r: p, c: d
        tile[r][c] = past_v[((size_t)bh * P_ + p0 + r) * 128 + d0 + c];
    }
    __syncthreads();
#pragma unroll
    for (int i = 0; i < 16; i++) {
        int idx = tid + i * 256;
        int r = idx >> 6, c = idx & 63;                // r: d, c: p
        Vt[((size_t)bh * 128 + d0 + r) * S_ + p0 + c] = f2bf(tile[c][r]);
    }
}

// ---------------------------------------------------------------- GEMM (3-buf)
// R9: reverted to 16x16x32 fragments (R6 state) -- the 32x32 frag reads were
// ~4-way bank-aliased and regressed ~13us. BM=256, BN=128, BK=64, NBUF=3
// (LDS 144 KiB). 8 waves (4m x 2n), per-wave 64x64 C. Counted-vmcnt pipeline
// (T4): iteration t waits vmcnt(6), issues tile t+2 into buf[(t+2)%3]. One
// barrier per K-step, no mid-loop drain. LDS rows 128 B, XOR-swizzle
// ((row&7)<<4) via pre-swizzled global source (rule #21).
template <typename OutT>
__global__ void __launch_bounds__(512, 1)
gemm3(const u16* __restrict__ A, const u16* __restrict__ Bt,
      OutT* __restrict__ Co, int Mdim, int Ndim, int Kdim) {
    __shared__ u16 lA[3 * 256 * 64];   // 96 KiB
    __shared__ u16 lB[3 * 128 * 64];   // 48 KiB
    const int nbx = Ndim >> 7;
    const int nwg = (Mdim >> 8) * nbx;
    int bid = blockIdx.x;
    int wg = (bid & 7) * (nwg >> 3) + (bid >> 3);      // XCD swizzle (nwg%8==0)
    const int bm = wg / nbx, bn = wg % nbx;
    const int m0 = bm << 8, n0 = bn << 7;
    const int tid = threadIdx.x;
    const int wave = tid >> 6, lane = tid & 63;
    const int mw = wave >> 1, nw = wave & 1;
    const int l15 = lane & 15, l4 = lane >> 4;

    f32x4 acc[4][4];
#pragma unroll
    for (int i = 0; i < 4; i++)
#pragma unroll
        for (int j = 0; j < 4; j++) acc[i][j] = (f32x4){0.f, 0.f, 0.f, 0.f};

    // staging sources: chunk cid = i*512 + tid; row = cid>>3, physical chunk
    // pc = cid&7 holds logical chunk pc^(row&7) (inverse-swizzled source).
    const u16* aSrc[4];
    const u16* bSrc[2];
#pragma unroll
    for (int i = 0; i < 4; i++) {
        int cid = i * 512 + tid;
        int r = cid >> 3, pc = cid & 7;
        aSrc[i] = A + (size_t)(m0 + r) * Kdim + ((pc ^ (r & 7)) << 3);
    }
#pragma unroll
    for (int i = 0; i < 2; i++) {
        int cid = i * 512 + tid;
        int r = cid >> 3, pc = cid & 7;
        bSrc[i] = Bt + (size_t)(n0 + r) * Kdim + ((pc ^ (r & 7)) << 3);
    }

#define STAGE3(bi, kt) do {                                                     \
    u16* _pa = lA + (bi) * 16384 + wave * 512;                                  \
    u16* _pb = lB + (bi) * 8192 + wave * 512;                                   \
    _Pragma("unroll")                                                           \
    for (int i = 0; i < 4; i++)                                                 \
        gload_lds16(aSrc[i] + (size_t)(kt) * 64, _pa + i * 4096);               \
    _Pragma("unroll")                                                           \
    for (int i = 0; i < 2; i++)                                                 \
        gload_lds16(bSrc[i] + (size_t)(kt) * 64, _pb + i * 4096);               \
} while (0)

    STAGE3(0, 0);
    STAGE3(1, 1);

    const int NT = Kdim >> 6;
    int bc = 0;
    for (int t = 0; t < NT; ++t) {
        if (t + 1 < NT) asm volatile("s_waitcnt vmcnt(6)" ::: "memory");
        else            asm volatile("s_waitcnt vmcnt(0)" ::: "memory");
        __builtin_amdgcn_s_barrier();
        asm volatile("" ::: "memory");
        if (t + 2 < NT) {
            int b2 = bc + 2; if (b2 >= 3) b2 -= 3;
            STAGE3(b2, t + 2);
        }
        const u16* la = lA + bc * 16384;
        const u16* lb = lB + bc * 8192;
        short8 af[4][2], bf[4][2];
#pragma unroll
        for (int i = 0; i < 4; i++)
#pragma unroll
            for (int kk = 0; kk < 2; kk++) {
                int r = mw * 64 + i * 16 + l15;
                int cb = (kk * 64 + l4 * 16) ^ ((r & 7) << 4);
                af[i][kk] = *(const short8*)&la[r * 64 + (cb >> 1)];
            }
#pragma unroll
        for (int j = 0; j < 4; j++)
#pragma unroll
            for (int kk = 0; kk < 2; kk++) {
                int r = nw * 64 + j * 16 + l15;
                int cb = (kk * 64 + l4 * 16) ^ ((r & 7) << 4);
                bf[j][kk] = *(const short8*)&lb[r * 64 + (cb >> 1)];
            }
        __builtin_amdgcn_s_setprio(1);
#pragma unroll
        for (int kk = 0; kk < 2; kk++)
#pragma unroll
            for (int i = 0; i < 4; i++)
#pragma unroll
                for (int j = 0; j < 4; j++)
                    acc[i][j] = mfma_bf16(af[i][kk], bf[j][kk], acc[i][j]);
        __builtin_amdgcn_s_setprio(0);
        __builtin_amdgcn_sched_barrier(0);   // rule #18: pin MFMA/lgkm here
        bc = bc + 1; if (bc >= 3) bc = 0;
    }
#undef STAGE3

    // epilogue
#pragma unroll
    for (int i = 0; i < 4; i++)
#pragma unroll
        for (int j = 0; j < 4; j++) {
            int row = m0 + mw * 64 + i * 16 + (l4 << 2);
            int col = n0 + nw * 64 + j * 16 + l15;
#pragma unroll
            for (int q = 0; q < 4; q++)
                storeC(&Co[(size_t)(row + q) * Ndim + col], acc[i][j][q]);
        }
}

// ---------------------------------------------------------------- attention
// R9: exact revert to R7 (V staged in LDS -- R8's V-from-global was
// uncoalesced VMEM, 160->257us). 4 waves x 32 q-rows = 128 q/block; 512
// blocks. Swapped QK^T / swapped PV, in-register softmax (max3-tree, 4-way
// partial sums, cvt_pk packing), T13 defer-max, K/V dbuf LDS + XOR-swizzle.
__global__ void __launch_bounds__(256, 2)
attn_kernel(const u16* __restrict__ QKVb, const u16* __restrict__ Kc,
            const u16* __restrict__ Vt, u16* __restrict__ O) {
    __shared__ u16 ldsK[2][64 * 128];   // [buf][64 k][128 d], rows 256B
    __shared__ u16 ldsV[2][128 * 64];   // [buf][128 d][64 k], rows 128B

    int bid = blockIdx.x;                              // 512 blocks
    int wg = (bid & 7) * 64 + (bid >> 3);              // XCD swizzle (bijective)
    const int qc = wg & 15;                            // q-chunk (16 x 128 rows)
    const int bh = wg >> 4;
    const int b = bh >> 4, h = bh & 15;
    const int tid = threadIdx.x, wave = tid >> 6, lane = tid & 63;
    const int l31 = lane & 31, hi = lane >> 5;

    // staging constants (256 thr): source pre-swizzled; LDS dest linear.
    const int krow = tid >> 4;                                         // 0..15
    const int kcol = (((tid & 15) << 4) ^ ((krow & 7) << 4)) >> 1;
    const int vrow = tid >> 3;                                         // 0..31
    const int vcol = (((tid & 7) << 4) ^ ((vrow & 7) << 4)) >> 1;

    const u16* Kbh = Kc + (size_t)bh * S_ * 128;
    const u16* Vbh = Vt + (size_t)bh * 128 * S_;

    const int tq = qc * 128 + wave * 32 + l31;         // this lane's q row
    // Q fragments: Q[q=l31][d = ks*16 + hi*8 + e], 8 x bf16x8
    short8 qf[8];
    {
        const u16* qp = QKVb + (size_t)(b * T_ + tq) * N3_ + h * 128 + hi * 8;
#pragma unroll
        for (int ks = 0; ks < 8; ks++) qf[ks] = *(const short8*)(qp + ks * 16);
    }

    f32x16 acco[4];                                    // O^T: col q=l31, row d
#pragma unroll
    for (int d = 0; d < 4; d++) acco[d] = (f32x16)(0.0f);
    float mrow = -1e30f, lrow = 0.f;                   // per-lane (q = l31)
    const float sl2 = 0.08838834764831845f * 1.4426950408889634f;

#define STAGE(bufi, tt) do {                                                    \
    const int _s0 = (tt) * 64;                                                  \
    _Pragma("unroll")                                                           \
    for (int i = 0; i < 4; i++)                                                 \
        gload_lds16(Kbh + (size_t)(_s0 + krow + i * 16) * 128 + kcol,           \
                    (char*)&ldsK[bufi][0] + i * 4096 + wave * 1024);            \
    _Pragma("unroll")                                                           \
    for (int i = 0; i < 4; i++)                                                 \
        gload_lds16(Vbh + (size_t)(vrow + i * 32) * S_ + _s0 + vcol,            \
                    (char*)&ldsV[bufi][0] + i * 4096 + wave * 1024);            \
} while (0)

    STAGE(0, 0);
    __syncthreads();

    const int swz = (l31 & 7) << 4;                    // read-side swizzle

    for (int t = 0; t < S_ / 64; ++t) {
        const int cur = t & 1;
        if (t < S_ / 64 - 1) STAGE(cur ^ 1, t + 1);

        const u16* Kl = ldsK[cur];
        const u16* Vl = ldsV[cur];

        // ---- QK^T: p0 (k 0..31), p1 (k 32..63); contraction d ----
        f32x16 p0 = (f32x16)(0.0f), p1 = (f32x16)(0.0f);
        __builtin_amdgcn_s_setprio(1);
#pragma unroll
        for (int ks = 0; ks < 8; ks++) {
            const int cidx = (((ks * 32 + hi * 16) ^ swz) >> 1);
            short8 k0 = *(const short8*)&Kl[(l31 << 7) + cidx];
            short8 k1 = *(const short8*)&Kl[((32 + l31) << 7) + cidx];
            p0 = mfma32(k0, qf[ks], p0);
            p1 = mfma32(k1, qf[ks], p1);
        }
        __builtin_amdgcn_s_setprio(0);

        // ---- online softmax, in-register (q = l31) ----
        float t0 = MAX3(p0[0], p0[1], p0[2]);
        float t1 = MAX3(p0[3], p0[4], p0[5]);
        float t2 = MAX3(p0[6], p0[7], p0[8]);
        float t3 = MAX3(p0[9], p0[10], p0[11]);
        float t4 = MAX3(p0[12], p0[13], p0[14]);
        float t5 = MAX3(p0[15], p1[0], p1[1]);
        float t6 = MAX3(p1[2], p1[3], p1[4]);
        float t7 = MAX3(p1[5], p1[6], p1[7]);
        float t8 = MAX3(p1[8], p1[9], p1[10]);
        float t9 = MAX3(p1[11], p1[12], p1[13]);
        float u0 = MAX3(t0, t1, t2);
        float u1 = MAX3(t3, t4, t5);
        float u2 = MAX3(t6, t7, t8);
        float u3 = MAX3(t9, p1[14], p1[15]);
        float pm = fmaxf(MAX3(u0, u1, u2), u3);
        pm = fmaxf(pm, __shfl_xor(pm, 32));
        float pmS = pm * sl2;
        if (!__all(pmS <= mrow + 8.0f)) {              // T13 defer-max
            float mn = fmaxf(mrow, pmS);
            float fac = exp2f(mrow - mn);
            mrow = mn;
            lrow *= fac;
#pragma unroll
            for (int d = 0; d < 4; d++)
#pragma unroll
                for (int r = 0; r < 16; r++) acco[d][r] *= fac;
        }
        float s0a = 0.f, s1a = 0.f, s2a = 0.f, s3a = 0.f;
#pragma unroll
        for (int r = 0; r < 16; r += 4) {
            p0[r + 0] = exp2f(fmaf(p0[r + 0], sl2, -mrow)); s0a += p0[r + 0];
            p0[r + 1] = exp2f(fmaf(p0[r + 1], sl2, -mrow)); s1a += p0[r + 1];
            p0[r + 2] = exp2f(fmaf(p0[r + 2], sl2, -mrow)); s2a += p0[r + 2];
            p0[r + 3] = exp2f(fmaf(p0[r + 3], sl2, -mrow)); s3a += p0[r + 3];
        }
#pragma unroll
        for (int r = 0; r < 16; r += 4) {
            p1[r + 0] = exp2f(fmaf(p1[r + 0], sl2, -mrow)); s0a += p1[r + 0];
            p1[r + 1] = exp2f(fmaf(p1[r + 1], sl2, -mrow)); s1a += p1[r + 1];
            p1[r + 2] = exp2f(fmaf(p1[r + 2], sl2, -mrow)); s2a += p1[r + 2];
            p1[r + 3] = exp2f(fmaf(p1[r + 3], sl2, -mrow)); s3a += p1[r + 3];
        }
        float sum = (s0a + s1a) + (s2a + s3a);
        sum += __shfl_xor(sum, 32);
        lrow += sum;

        // ---- P (C-layout) -> PV B-frags, in-register (T12: cvt_pk + shfl) ----
        uint32 w[4][4];
#define PACK_HALF(pp, kh, ksout) do {                                           \
    uint32 A0 = cvtpk(pp[(kh)*8 + 0], pp[(kh)*8 + 1]);                          \
    uint32 A1 = cvtpk(pp[(kh)*8 + 2], pp[(kh)*8 + 3]);                          \
    uint32 B0 = cvtpk(pp[(kh)*8 + 4], pp[(kh)*8 + 5]);                          \
    uint32 B1 = cvtpk(pp[(kh)*8 + 6], pp[(kh)*8 + 7]);                          \
    uint32 sA0 = __shfl_xor(A0, 32), sA1 = __shfl_xor(A1, 32);                  \
    uint32 sB0 = __shfl_xor(B0, 32), sB1 = __shfl_xor(B1, 32);                  \
    w[ksout][0] = hi ? sB0 : A0;                                                \
    w[ksout][1] = hi ? sB1 : A1;                                                \
    w[ksout][2] = hi ? B0 : sA0;                                                \
    w[ksout][3] = hi ? B1 : sA1;                                                \
} while (0)
        PACK_HALF(p0, 0, 0);
        PACK_HALF(p0, 1, 1);
        PACK_HALF(p1, 0, 2);
        PACK_HALF(p1, 1, 3);
#undef PACK_HALF

        // ---- PV: O^T[d][q] += V^T[d][k] * P^T[k][q] ----
        __builtin_amdgcn_s_setprio(1);
#pragma unroll
        for (int ks = 0; ks < 4; ks++) {
            uint4v pw = {w[ks][0], w[ks][1], w[ks][2], w[ks][3]};
            short8 pf = __builtin_bit_cast(short8, pw);
            const int cidx = (((ks * 32 + hi * 16) ^ swz) >> 1);
#pragma unroll
            for (int dblk = 0; dblk < 4; dblk++) {
                short8 vf = *(const short8*)&Vl[((dblk * 32 + l31) << 6) + cidx];
                acco[dblk] = mfma32(vf, pf, acco[dblk]);
            }
        }
        __builtin_amdgcn_s_setprio(0);

        __syncthreads();   // readers done with cur; stage(cur^1) drained
    }
#undef STAGE

    // ---- epilogue: O[b*T+tq][h*128+d], d = dblk*32 + 8*j + 4*hi + {0..3} ----
    float rl = 1.0f / lrow;
    u16* Op = O + (size_t)(b * T_ + tq) * C_ + h * 128;
#pragma unroll
    for (int dblk = 0; dblk < 4; dblk++)
#pragma unroll
        for (int j = 0; j < 4; j++) {
            u16x4 o;
            o.x = f2bf(acco[dblk][4 * j + 0] * rl);
            o.y = f2bf(acco[dblk][4 * j + 1] * rl);
            o.z = f2bf(acco[dblk][4 * j + 2] * rl);
            o.w = f2bf(acco[dblk][4 * j + 3] * rl);
            *(u16x4*)(Op + dblk * 32 + j * 8 + hi * 4) = o;
        }
}

// ---------------------------------------------------------------- launch

extern "C" void kernel_launch(void* const* d_in, const int* in_sizes, int n_in,
                              void* d_out, int out_size, void* d_ws, size_t ws_size,
                              hipStream_t stream) {
    const float* x      = (const float*)d_in[0];
    const float* w_qkv  = (const float*)d_in[1];
    const float* w_out  = (const float*)d_in[2];
    const float* past_k = (const float*)d_in[3];
    const float* past_v = (const float*)d_in[4];
    float* out = (float*)d_out;

    char* ws = (char*)d_ws;
    u16* Xb    = (u16*)(ws);                            // 16 MB
    u16* Wqkvt = (u16*)(ws + 16777216);                 // 24 MB
    u16* Woutt = (u16*)(ws + 41943040);                 //  8 MB
    u16* QKVb  = (u16*)(ws + 50331648);                 // 48 MB
    u16* Kc    = (u16*)(ws + 100663296);                // 24 MB
    u16* Vt    = (u16*)(ws + 125829120);                // 24 MB
    u16* O     = (u16*)(ws + 150994944);                // 16 MB
    float* cosT = (float*)(ws + 167772160);             // 0.5 MB
    float* sinT = (float*)(ws + 168296448);             // 0.5 MB

    castx_kernel<<<(M_ * C_ / 4) / 256, 256, 0, stream>>>(x, Xb);
    wT_kernel<<<dim3(N3_ / 64, C_ / 64), 256, 0, stream>>>(w_qkv, Wqkvt, N3_, C_);
    wT_kernel<<<dim3(C_ / 64, C_ / 64), 256, 0, stream>>>(w_out, Woutt, C_, C_);
    rope_table_kernel<<<(T_ * 64) / 256, 256, 0, stream>>>(cosT, sinT);

    gemm3<u16><<<(M_ / 256) * (N3_ / 128), 512, 0, stream>>>(Xb, Wqkvt, QKVb, M_, N3_, C_);

    rope_qk_kernel<<<(B_ * T_ * H_ * 64) / 256, 256, 0, stream>>>(QKVb, Kc, cosT, sinT);
    pastk_kernel<<<(B_ * H_ * P_ * D_) / 256, 256, 0, stream>>>(past_k, Kc);
    vnewT_kernel<<<dim3(T_ / 64, 2, B_ * H_), 256, 0, stream>>>(QKVb, Vt);
    vpastT_kernel<<<dim3(P_ / 64, 2, B_ * H_), 256, 0, stream>>>(past_v, Vt);

    attn_kernel<<<512, 256, 0, stream>>>(QKVb, Kc, Vt, O);

    gemm3<float><<<(M_ / 256) * (C_ / 128), 512, 0, stream>>>(O, Woutt, out, M_, C_, C_);
}